// Round 1
// baseline (6703.221 us; speedup 1.0000x reference)
//
#include <hip/hip_runtime.h>
#include <hip/hip_bf16.h>
#include <cstdint>
#include <cstddef>

#define NDIM 8192
#define ROWS_PER_BLOCK 8
#define ITERS 20

// ---------- helpers ----------
__device__ __forceinline__ unsigned short f2bf_rne(float f) {
  // round-to-nearest-even fp32 -> bf16 (inputs are positive finite, no NaN)
  unsigned int u = __float_as_uint(f);
  unsigned int r = 0x7fffu + ((u >> 16) & 1u);
  return (unsigned short)((u + r) >> 16);
}
__device__ __forceinline__ float bflo(unsigned int u) { return __uint_as_float(u << 16); }
__device__ __forceinline__ float bfhi(unsigned int u) { return __uint_as_float(u & 0xffff0000u); }

// ---------- kernels ----------
__global__ void k_init_colsum(float* __restrict__ colsum) {
  int j = blockIdx.x * blockDim.x + threadIdx.x;  // launched with exactly NDIM threads
  colsum[j] = 1.0f;                                // so first b = 1/colsum = 1
}

// E_bf16 = bf16(exp(H))   (E stored in first 128MB of d_out)
__global__ void k_exp_bf16(const float* __restrict__ H, unsigned short* __restrict__ E) {
  const size_t nv = (size_t)NDIM * NDIM / 4;
  const size_t stride = (size_t)gridDim.x * blockDim.x;
  for (size_t v = (size_t)blockIdx.x * blockDim.x + threadIdx.x; v < nv; v += stride) {
    float4 h = reinterpret_cast<const float4*>(H)[v];
    ushort4 o;
    o.x = f2bf_rne(__expf(h.x));
    o.y = f2bf_rne(__expf(h.y));
    o.z = f2bf_rne(__expf(h.z));
    o.w = f2bf_rne(__expf(h.w));
    reinterpret_cast<ushort4*>(E)[v] = o;
  }
}

// b[j] = 1/colsum[j]; colsum[j] = 0   (launched with exactly NDIM threads)
__global__ void k_invert_zero(float* __restrict__ colsum, float* __restrict__ b) {
  int j = blockIdx.x * blockDim.x + threadIdx.x;
  b[j] = 1.0f / colsum[j];
  colsum[j] = 0.0f;
}

// Fused per-iteration pass:
//   for each row i in this block's 8 rows:
//     a[i] = 1 / (E_row_i . b)          (row normalization factor)
//     colsum[j] += a[i] * E[i][j]        (accumulated in registers, atomic flush)
// Thread t owns columns j = 2048*c + 8*t + r  (c=0..3, r=0..7)  -> 32 j's.
__global__ void k_fused(const unsigned short* __restrict__ E,
                        const float* __restrict__ b,
                        float* __restrict__ a,
                        float* __restrict__ colsum) {
  const int t = threadIdx.x;                       // 0..255
  const int row0 = blockIdx.x * ROWS_PER_BLOCK;

  // load b into registers (block-invariant)
  float breg[4][8];
#pragma unroll
  for (int c = 0; c < 4; ++c) {
    const float4* bp = reinterpret_cast<const float4*>(b + 2048 * c + 8 * t);
    float4 b0 = bp[0], b1 = bp[1];
    breg[c][0] = b0.x; breg[c][1] = b0.y; breg[c][2] = b0.z; breg[c][3] = b0.w;
    breg[c][4] = b1.x; breg[c][5] = b1.y; breg[c][6] = b1.z; breg[c][7] = b1.w;
  }

  float cs[4][8];
#pragma unroll
  for (int c = 0; c < 4; ++c)
#pragma unroll
    for (int r = 0; r < 8; ++r) cs[c][r] = 0.0f;

  __shared__ float red[4];
  __shared__ float a_bc;

  for (int rr = 0; rr < ROWS_PER_BLOCK; ++rr) {
    const int i = row0 + rr;
    const unsigned short* rowp = E + (size_t)i * NDIM;

    float e[4][8];
#pragma unroll
    for (int c = 0; c < 4; ++c) {
      uint4 u = *reinterpret_cast<const uint4*>(rowp + 2048 * c + 8 * t);
      e[c][0] = bflo(u.x); e[c][1] = bfhi(u.x);
      e[c][2] = bflo(u.y); e[c][3] = bfhi(u.y);
      e[c][4] = bflo(u.z); e[c][5] = bfhi(u.z);
      e[c][6] = bflo(u.w); e[c][7] = bfhi(u.w);
    }

    float dot = 0.0f;
#pragma unroll
    for (int c = 0; c < 4; ++c)
#pragma unroll
      for (int r = 0; r < 8; ++r) dot += e[c][r] * breg[c][r];

    // wave64 butterfly reduce
#pragma unroll
    for (int m = 32; m >= 1; m >>= 1) dot += __shfl_xor(dot, m, 64);
    if ((t & 63) == 0) red[t >> 6] = dot;
    __syncthreads();
    if (t == 0) {
      float s = red[0] + red[1] + red[2] + red[3];
      float ai = 1.0f / s;
      a[i] = ai;
      a_bc = ai;
    }
    __syncthreads();
    const float ai = a_bc;

#pragma unroll
    for (int c = 0; c < 4; ++c)
#pragma unroll
      for (int r = 0; r < 8; ++r) cs[c][r] += ai * e[c][r];
    // no barrier needed here: next row's red/a_bc writes are ordered by the
    // __syncthreads() above relative to this row's reads.
  }

#pragma unroll
  for (int c = 0; c < 4; ++c)
#pragma unroll
    for (int r = 0; r < 8; ++r)
      atomicAdd(&colsum[2048 * c + 8 * t + r], cs[c][r]);
}

// out[i][j] = exp(H[i][j]) * a[i] * b[j]   (fp32, overwrites E region — E is dead)
__global__ void k_final(const float* __restrict__ H,
                        const float* __restrict__ a,
                        const float* __restrict__ b,
                        float* __restrict__ out) {
  const size_t nv = (size_t)NDIM * NDIM / 4;
  const size_t stride = (size_t)gridDim.x * blockDim.x;
  for (size_t v = (size_t)blockIdx.x * blockDim.x + threadIdx.x; v < nv; v += stride) {
    float4 h = reinterpret_cast<const float4*>(H)[v];
    const int i = (int)(v >> 11);          // v / (8192/4)
    const int jv = (int)(v & 2047);
    float4 bb = reinterpret_cast<const float4*>(b)[jv];
    const float ai = a[i];
    float4 o;
    o.x = __expf(h.x) * ai * bb.x;
    o.y = __expf(h.y) * ai * bb.y;
    o.z = __expf(h.z) * ai * bb.z;
    o.w = __expf(h.w) * ai * bb.w;
    reinterpret_cast<float4*>(out)[v] = o;
  }
}

// ---------- launch ----------
extern "C" void kernel_launch(void* const* d_in, const int* in_sizes, int n_in,
                              void* d_out, int out_size, void* d_ws, size_t ws_size,
                              hipStream_t stream) {
  const float* H = (const float*)d_in[0];
  float* out = (float*)d_out;
  unsigned short* E = (unsigned short*)d_out;   // bf16 E in first half of d_out
  float* a = (float*)d_ws;                      // [NDIM]
  float* b = a + NDIM;                          // [NDIM]
  float* colsum = b + NDIM;                     // [NDIM]   (total 96KB of ws)

  k_init_colsum<<<NDIM / 256, 256, 0, stream>>>(colsum);
  k_exp_bf16<<<2048, 256, 0, stream>>>(H, E);

  for (int it = 0; it < ITERS; ++it) {
    k_invert_zero<<<NDIM / 256, 256, 0, stream>>>(colsum, b);
    k_fused<<<NDIM / ROWS_PER_BLOCK, 256, 0, stream>>>(E, b, a, colsum);
  }
  k_invert_zero<<<NDIM / 256, 256, 0, stream>>>(colsum, b);  // b = 1/(E^T a_20)
  k_final<<<2048, 256, 0, stream>>>(H, a, b, out);
}

// Round 2
// 1380.885 us; speedup vs baseline: 4.8543x; 4.8543x over previous
//
#include <hip/hip_runtime.h>
#include <hip/hip_bf16.h>
#include <cstdint>
#include <cstddef>

#define NDIM 8192
#define ITERS 20
#define RB 32   // rows per k_colacc block

// ---------- helpers ----------
__device__ __forceinline__ unsigned short f2bf_rne(float f) {
  unsigned int u = __float_as_uint(f);
  unsigned int r = 0x7fffu + ((u >> 16) & 1u);
  return (unsigned short)((u + r) >> 16);
}
__device__ __forceinline__ float bflo(unsigned int u) { return __uint_as_float(u << 16); }
__device__ __forceinline__ float bfhi(unsigned int u) { return __uint_as_float(u & 0xffff0000u); }

// ---------- kernels ----------
__global__ void k_init_b(float* __restrict__ b) {
  int j = blockIdx.x * blockDim.x + threadIdx.x;  // exactly NDIM threads
  b[j] = 1.0f;
}

// E = bf16(exp(H))  (first 128MB of d_out)
__global__ void k_exp_bf16(const float* __restrict__ H, unsigned short* __restrict__ E) {
  const size_t nv = (size_t)NDIM * NDIM / 4;
  const size_t stride = (size_t)gridDim.x * blockDim.x;
  for (size_t v = (size_t)blockIdx.x * blockDim.x + threadIdx.x; v < nv; v += stride) {
    float4 h = reinterpret_cast<const float4*>(H)[v];
    ushort4 o;
    o.x = f2bf_rne(__expf(h.x));
    o.y = f2bf_rne(__expf(h.y));
    o.z = f2bf_rne(__expf(h.z));
    o.w = f2bf_rne(__expf(h.w));
    reinterpret_cast<ushort4*>(E)[v] = o;
  }
}

// a[i] = 1 / (E_row_i . b)   — one wave per row, no LDS, no barriers.
__global__ void k_rowdot(const unsigned short* __restrict__ E,
                         const float* __restrict__ b,
                         float* __restrict__ a) {
  const int wave = threadIdx.x >> 6;        // 0..3
  const int lane = threadIdx.x & 63;
  const int row = blockIdx.x * 4 + wave;
  const unsigned short* rowp = E + (size_t)row * NDIM;

  float acc[8];
#pragma unroll
  for (int r = 0; r < 8; ++r) acc[r] = 0.0f;

#pragma unroll
  for (int c = 0; c < 16; ++c) {
    const int u = c * 64 + lane;            // uint4 index within row (0..1023)
    uint4 ev = reinterpret_cast<const uint4*>(rowp)[u];
    const float4* bp = reinterpret_cast<const float4*>(b) + (size_t)u * 2;
    float4 b0 = bp[0], b1 = bp[1];
    acc[0] += bflo(ev.x) * b0.x; acc[1] += bfhi(ev.x) * b0.y;
    acc[2] += bflo(ev.y) * b0.z; acc[3] += bfhi(ev.y) * b0.w;
    acc[4] += bflo(ev.z) * b1.x; acc[5] += bfhi(ev.z) * b1.y;
    acc[6] += bflo(ev.w) * b1.z; acc[7] += bfhi(ev.w) * b1.w;
  }
  float dot = ((acc[0] + acc[1]) + (acc[2] + acc[3])) +
              ((acc[4] + acc[5]) + (acc[6] + acc[7]));
#pragma unroll
  for (int m = 32; m >= 1; m >>= 1) dot += __shfl_xor(dot, m, 64);
  if (lane == 0) a[row] = 1.0f / dot;
}

// partial[rc][j] = sum_{i in chunk rc} a[i] * E[i][j]
// grid: 1024 blocks = 4 col-stripes x 256 row-chunks (RB=32 rows each).
// Thread owns 8 consecutive columns; inner loop = 32 independent uint4 loads.
__global__ void k_colacc(const unsigned short* __restrict__ E,
                         const float* __restrict__ a,
                         float* __restrict__ partial) {
  const int t = threadIdx.x;
  const int stripe = blockIdx.x & 3;        // 0..3
  const int rc = blockIdx.x >> 2;           // 0..255
  const int j0 = stripe * 2048 + t * 8;
  const int i0 = rc * RB;

  float cs[8];
#pragma unroll
  for (int r = 0; r < 8; ++r) cs[r] = 0.0f;

#pragma unroll
  for (int ii = 0; ii < RB; ++ii) {
    const float ai = a[i0 + ii];            // uniform -> scalar load
    uint4 ev = *reinterpret_cast<const uint4*>(E + (size_t)(i0 + ii) * NDIM + j0);
    cs[0] += ai * bflo(ev.x); cs[1] += ai * bfhi(ev.x);
    cs[2] += ai * bflo(ev.y); cs[3] += ai * bfhi(ev.y);
    cs[4] += ai * bflo(ev.z); cs[5] += ai * bfhi(ev.z);
    cs[6] += ai * bflo(ev.w); cs[7] += ai * bfhi(ev.w);
  }
  float4* pp = reinterpret_cast<float4*>(partial + (size_t)rc * NDIM + j0);
  pp[0] = float4{cs[0], cs[1], cs[2], cs[3]};
  pp[1] = float4{cs[4], cs[5], cs[6], cs[7]};
}

// b[j] = 1 / sum_{rc} partial[rc][j]   (256 partials, 8MB read)
__global__ void k_reduce_b(const float* __restrict__ partial, float* __restrict__ b) {
  const int j = blockIdx.x * blockDim.x + threadIdx.x;   // exactly NDIM threads
  float s0 = 0.0f, s1 = 0.0f, s2 = 0.0f, s3 = 0.0f;
#pragma unroll 4
  for (int p = 0; p < 256; p += 4) {
    s0 += partial[(size_t)(p + 0) * NDIM + j];
    s1 += partial[(size_t)(p + 1) * NDIM + j];
    s2 += partial[(size_t)(p + 2) * NDIM + j];
    s3 += partial[(size_t)(p + 3) * NDIM + j];
  }
  b[j] = 1.0f / ((s0 + s1) + (s2 + s3));
}

// out[i][j] = exp(H[i][j]) * a[i] * b[j]  (fp32; overwrites E/partial — both dead)
__global__ void k_final(const float* __restrict__ H,
                        const float* __restrict__ a,
                        const float* __restrict__ b,
                        float* __restrict__ out) {
  const size_t nv = (size_t)NDIM * NDIM / 4;
  const size_t stride = (size_t)gridDim.x * blockDim.x;
  for (size_t v = (size_t)blockIdx.x * blockDim.x + threadIdx.x; v < nv; v += stride) {
    float4 h = reinterpret_cast<const float4*>(H)[v];
    const int i = (int)(v >> 11);
    const int jv = (int)(v & 2047);
    float4 bb = reinterpret_cast<const float4*>(b)[jv];
    const float ai = a[i];
    float4 o;
    o.x = __expf(h.x) * ai * bb.x;
    o.y = __expf(h.y) * ai * bb.y;
    o.z = __expf(h.z) * ai * bb.z;
    o.w = __expf(h.w) * ai * bb.w;
    reinterpret_cast<float4*>(out)[v] = o;
  }
}

// ---------- launch ----------
extern "C" void kernel_launch(void* const* d_in, const int* in_sizes, int n_in,
                              void* d_out, int out_size, void* d_ws, size_t ws_size,
                              hipStream_t stream) {
  const float* H = (const float*)d_in[0];
  float* out = (float*)d_out;
  unsigned short* E = (unsigned short*)d_out;                    // 128MB bf16
  float* partial = (float*)((char*)d_out + (size_t)NDIM * NDIM * 2);  // 8MB in 2nd half
  float* a = (float*)d_ws;                                       // [NDIM]
  float* b = a + NDIM;                                           // [NDIM]

  k_init_b<<<NDIM / 256, 256, 0, stream>>>(b);
  k_exp_bf16<<<2048, 256, 0, stream>>>(H, E);

  for (int it = 0; it < ITERS; ++it) {
    k_rowdot<<<NDIM / 4, 256, 0, stream>>>(E, b, a);
    k_colacc<<<1024, 256, 0, stream>>>(E, a, partial);
    k_reduce_b<<<NDIM / 256, 256, 0, stream>>>(partial, b);
  }
  k_final<<<2048, 256, 0, stream>>>(H, a, b, out);
}

// Round 3
// 1039.688 us; speedup vs baseline: 6.4473x; 1.3282x over previous
//
#include <hip/hip_runtime.h>
#include <cstdint>
#include <cstddef>

#define NDIM 8192
#define NITER 20

// ---------- helpers ----------
__device__ __forceinline__ unsigned short f2bf_rne(float f) {
  unsigned int u = __float_as_uint(f);
  unsigned int r = 0x7fffu + ((u >> 16) & 1u);
  return (unsigned short)((u + r) >> 16);
}
__device__ __forceinline__ unsigned int pack2(float lo, float hi) {
  return (unsigned int)f2bf_rne(lo) | ((unsigned int)f2bf_rne(hi) << 16);
}
__device__ __forceinline__ float bflo(unsigned int u) { return __uint_as_float(u << 16); }
__device__ __forceinline__ float bfhi(unsigned int u) { return __uint_as_float(u & 0xffff0000u); }

// Block-wide reduction: each thread holds partial dots for the block's 8 rows
// (over its 8 columns). Produces 1/rowsum in ash[0..7] and writes a_out.
// Exactly 2 barriers.
__device__ __forceinline__ void rows8_reduce(float (&dots)[8], float* ash,
                                             float* __restrict__ a_out, int i0) {
  const int t = threadIdx.x;
#pragma unroll
  for (int r = 0; r < 8; ++r)
#pragma unroll
    for (int m = 32; m >= 1; m >>= 1)
      dots[r] += __shfl_xor(dots[r], m, 64);
  __shared__ float red[16][8];
  const int w = t >> 6;
  if ((t & 63) == 0) {
#pragma unroll
    for (int r = 0; r < 8; ++r) red[w][r] = dots[r];
  }
  __syncthreads();
  if (t < 8) {
    float s = 0.0f;
#pragma unroll
    for (int ww = 0; ww < 16; ++ww) s += red[ww][t];
    float inv = 1.0f / s;
    ash[t] = inv;
    a_out[i0 + t] = inv;
  }
  __syncthreads();
}

// ---------- kernels ----------

// Iteration 1 fused with exp: reads H, writes E=bf16(exp(H)), computes
// a = 1/rowsum(exp(H)) (b==1), and column partials for this 8-row chunk.
__global__ __launch_bounds__(1024) void k_first(const float* __restrict__ H,
                                                unsigned short* __restrict__ E,
                                                float* __restrict__ a,
                                                float* __restrict__ partial) {
  const int t = threadIdx.x;
  const int i0 = blockIdx.x * 8;
  const int j0 = t * 8;
  __shared__ float ash[8];

  float e[8][8];
  float dots[8];
#pragma unroll
  for (int r = 0; r < 8; ++r) {
    const float* hp = H + (size_t)(i0 + r) * NDIM + j0;
    float4 h0 = reinterpret_cast<const float4*>(hp)[0];
    float4 h1 = reinterpret_cast<const float4*>(hp)[1];
    e[r][0] = __expf(h0.x); e[r][1] = __expf(h0.y);
    e[r][2] = __expf(h0.z); e[r][3] = __expf(h0.w);
    e[r][4] = __expf(h1.x); e[r][5] = __expf(h1.y);
    e[r][6] = __expf(h1.z); e[r][7] = __expf(h1.w);
    uint4 o{pack2(e[r][0], e[r][1]), pack2(e[r][2], e[r][3]),
            pack2(e[r][4], e[r][5]), pack2(e[r][6], e[r][7])};
    *reinterpret_cast<uint4*>(E + (size_t)(i0 + r) * NDIM + j0) = o;
    dots[r] = ((e[r][0] + e[r][1]) + (e[r][2] + e[r][3])) +
              ((e[r][4] + e[r][5]) + (e[r][6] + e[r][7]));
  }

  rows8_reduce(dots, ash, a, i0);

  float cs[8];
#pragma unroll
  for (int k = 0; k < 8; ++k) cs[k] = 0.0f;
#pragma unroll
  for (int r = 0; r < 8; ++r) {
    const float ai = ash[r];
#pragma unroll
    for (int k = 0; k < 8; ++k) cs[k] += ai * e[r][k];
  }
  float4* pp = reinterpret_cast<float4*>(partial + (size_t)blockIdx.x * NDIM + j0);
  pp[0] = float4{cs[0], cs[1], cs[2], cs[3]};
  pp[1] = float4{cs[4], cs[5], cs[6], cs[7]};
}

// Generic iteration: ONE pass over E. Block = 8 full rows; thread owns 8 cols.
// dots from registers -> block reduce -> colacc from the same registers.
__global__ __launch_bounds__(1024) void k_iter(const unsigned short* __restrict__ E,
                                               const float* __restrict__ b,
                                               float* __restrict__ a,
                                               float* __restrict__ partial) {
  const int t = threadIdx.x;
  const int i0 = blockIdx.x * 8;
  const int j0 = t * 8;
  __shared__ float ash[8];

  const float4* bp = reinterpret_cast<const float4*>(b + j0);
  float4 b0 = bp[0], b1 = bp[1];
  float breg[8] = {b0.x, b0.y, b0.z, b0.w, b1.x, b1.y, b1.z, b1.w};

  float e[8][8];
  float dots[8];
#pragma unroll
  for (int r = 0; r < 8; ++r) {
    uint4 ev = *reinterpret_cast<const uint4*>(E + (size_t)(i0 + r) * NDIM + j0);
    e[r][0] = bflo(ev.x); e[r][1] = bfhi(ev.x);
    e[r][2] = bflo(ev.y); e[r][3] = bfhi(ev.y);
    e[r][4] = bflo(ev.z); e[r][5] = bfhi(ev.z);
    e[r][6] = bflo(ev.w); e[r][7] = bfhi(ev.w);
    float d = 0.0f;
#pragma unroll
    for (int k = 0; k < 8; ++k) d += e[r][k] * breg[k];
    dots[r] = d;
  }

  rows8_reduce(dots, ash, a, i0);

  float cs[8];
#pragma unroll
  for (int k = 0; k < 8; ++k) cs[k] = 0.0f;
#pragma unroll
  for (int r = 0; r < 8; ++r) {
    const float ai = ash[r];
#pragma unroll
    for (int k = 0; k < 8; ++k) cs[k] += ai * e[r][k];
  }
  float4* pp = reinterpret_cast<float4*>(partial + (size_t)blockIdx.x * NDIM + j0);
  pp[0] = float4{cs[0], cs[1], cs[2], cs[3]};
  pp[1] = float4{cs[4], cs[5], cs[6], cs[7]};
}

// seg[s][j] = sum of 128 chunk partials.  grid = 8 segs x 32 colblocks.
__global__ void k_reduceA(const float* __restrict__ partial, float* __restrict__ seg) {
  const int t = threadIdx.x;             // 256
  const int s = blockIdx.x >> 5;
  const int c = blockIdx.x & 31;
  const int j = c * 256 + t;
  float acc[8];
#pragma unroll
  for (int q = 0; q < 8; ++q) acc[q] = 0.0f;
#pragma unroll 4
  for (int k = 0; k < 128; k += 8) {
#pragma unroll
    for (int q = 0; q < 8; ++q)
      acc[q] += partial[(size_t)(s * 128 + k + q) * NDIM + j];
  }
  seg[(size_t)s * NDIM + j] =
      ((acc[0] + acc[1]) + (acc[2] + acc[3])) + ((acc[4] + acc[5]) + (acc[6] + acc[7]));
}

// b[j] = 1 / sum_s seg[s][j]
__global__ void k_reduceB(const float* __restrict__ seg, float* __restrict__ b) {
  const int j = blockIdx.x * blockDim.x + threadIdx.x;   // exactly NDIM threads
  float s = 0.0f;
#pragma unroll
  for (int ss = 0; ss < 8; ++ss) s += seg[(size_t)ss * NDIM + j];
  b[j] = 1.0f / s;
}

// out[i][j] = exp(H[i][j]) * a[i] * b[j]  (fp32; overwrites E/partial/seg — all dead)
__global__ void k_final(const float* __restrict__ H,
                        const float* __restrict__ a,
                        const float* __restrict__ b,
                        float* __restrict__ out) {
  const size_t nv = (size_t)NDIM * NDIM / 4;
  const size_t stride = (size_t)gridDim.x * blockDim.x;
  for (size_t v = (size_t)blockIdx.x * blockDim.x + threadIdx.x; v < nv; v += stride) {
    float4 h = reinterpret_cast<const float4*>(H)[v];
    const int i = (int)(v >> 11);
    const int jv = (int)(v & 2047);
    float4 bb = reinterpret_cast<const float4*>(b)[jv];
    const float ai = a[i];
    float4 o;
    o.x = __expf(h.x) * ai * bb.x;
    o.y = __expf(h.y) * ai * bb.y;
    o.z = __expf(h.z) * ai * bb.z;
    o.w = __expf(h.w) * ai * bb.w;
    reinterpret_cast<float4*>(out)[v] = o;
  }
}

// ---------- launch ----------
extern "C" void kernel_launch(void* const* d_in, const int* in_sizes, int n_in,
                              void* d_out, int out_size, void* d_ws, size_t ws_size,
                              hipStream_t stream) {
  const float* H = (const float*)d_in[0];
  float* out = (float*)d_out;
  unsigned short* E = (unsigned short*)d_out;                          // 128MB bf16
  float* partial = (float*)((char*)d_out + (size_t)NDIM * NDIM * 2);   // 32MB
  float* seg = (float*)((char*)d_out + (size_t)NDIM * NDIM * 2 + (size_t)1024 * NDIM * 4); // 256KB
  float* a = (float*)d_ws;                                             // [NDIM]
  float* b = a + NDIM;                                                 // [NDIM]

  // iteration 1 (b == 1), fused with exp
  k_first<<<NDIM / 8, 1024, 0, stream>>>(H, E, a, partial);
  k_reduceA<<<256, 256, 0, stream>>>(partial, seg);
  k_reduceB<<<NDIM / 256, 256, 0, stream>>>(seg, b);

  // iterations 2..20
  for (int it = 1; it < NITER; ++it) {
    k_iter<<<NDIM / 8, 1024, 0, stream>>>(E, b, a, partial);
    k_reduceA<<<256, 256, 0, stream>>>(partial, seg);
    k_reduceB<<<NDIM / 256, 256, 0, stream>>>(seg, b);
  }

  k_final<<<2048, 256, 0, stream>>>(H, a, b, out);
}